// Round 4
// baseline (137.222 us; speedup 1.0000x reference)
//
#include <hip/hip_runtime.h>
#include <hip/hip_bf16.h>
#include <math.h>

// B=256, C=4, N=64, F=256, OC=8, OF=256
// d_out = out (256*2048 f32) then adj (256*4*256*256 f32).

typedef __bf16 bf16x8 __attribute__((ext_vector_type(8)));
typedef __bf16 bf16x4 __attribute__((ext_vector_type(4)));
typedef float f32x4 __attribute__((ext_vector_type(4)));

#define NB 256
#define NC 4
#define NN 64
#define NF 256
#define NO 2048

// ============ Kernel 1 (fused): s1, s2, Wc->bf16, x->zbf ============
// blocks [0,16384): s2[b,n]   [16384,16640): s1[b]
// blocks [16640,20736): cvt Wc   [20736,20992): cvt x into zbf[:,1024:]
__global__ __launch_bounds__(256) void k_pre(
    const float* __restrict__ x, const float* __restrict__ nb,
    const float* __restrict__ W1, const float* __restrict__ W2,
    const float* __restrict__ Wc,
    __hip_bfloat16* __restrict__ Wcb, __hip_bfloat16* __restrict__ zbf,
    float* __restrict__ s1, float* __restrict__ s2)
{
  __shared__ float red[4];
  int t = threadIdx.x;
  int gid = blockIdx.x;

  if (gid < 16640) {
    int fi = t & 63;                       // f4 index within the F dimension
    const float4* Wf4 = (const float4*)((gid < 16384) ? W2 : W1);
    float4 w0 = Wf4[fi], w1 = Wf4[64 + fi], w2 = Wf4[128 + fi], w3 = Wf4[192 + fi];
    float4 wv = { w0.x + w1.x + w2.x + w3.x,
                  w0.y + w1.y + w2.y + w3.y,
                  w0.z + w1.z + w2.z + w3.z,
                  w0.w + w1.w + w2.w + w3.w };   // sum over C (weight cols)
    const float4* src = (gid < 16384) ? ((const float4*)nb + (size_t)gid * 256)
                                      : ((const float4*)x + (size_t)(gid - 16384) * 256);
    float4 nv = src[t];
    float val = fmaf(nv.x, wv.x, fmaf(nv.y, wv.y, fmaf(nv.z, wv.z, nv.w * wv.w)));
    for (int off = 32; off > 0; off >>= 1) val += __shfl_down(val, off);
    if ((t & 63) == 0) red[t >> 6] = val;
    __syncthreads();
    if (t == 0) {
      float s = red[0] + red[1] + red[2] + red[3];
      if (gid < 16384) s2[gid] = s;
      else s1[gid - 16384] = s;
    }
  } else if (gid < 20736) {
    int idx = (gid - 16640) * 256 + t;
    float4 v = ((const float4*)Wc)[idx];
    bf16x4 o = { (__bf16)v.x, (__bf16)v.y, (__bf16)v.z, (__bf16)v.w };
    ((bf16x4*)Wcb)[idx] = o;
  } else {
    int i = (gid - 20736) * 256 + t;       // float4 index into x
    int e = i * 4;
    int b = e >> 10, r = e & 1023;
    float4 v = ((const float4*)x)[i];
    bf16x4 o = { (__bf16)v.x, (__bf16)v.y, (__bf16)v.z, (__bf16)v.w };
    *(bf16x4*)(zbf + (size_t)b * 2048 + 1024 + r) = o;
  }
}

// ============ Kernel 2: softmax + nw + inv + h (no big stores) ============
// One block per (b,c). Writes nsArr/invArr (ws) and h into zbf[:, :1024].
__global__ __launch_bounds__(256) void k_nw(
    const float* __restrict__ x, const float* __restrict__ nb,
    const float* __restrict__ s1, const float* __restrict__ s2,
    float* __restrict__ nsArr, float* __restrict__ invArr,
    __hip_bfloat16* __restrict__ zbf)
{
  __shared__ float xs[256], ns[256], invs[256], wsh[64];
  __shared__ float part[4][256];
  int t = threadIdx.x;
  int w = t >> 6, l = t & 63;
  int blk = blockIdx.x;
  int b = blk >> 2, c = blk & 3;

  if (t < 64) {
    float v = s1[b] * s2[b * 64 + t];
    float m = v;
    for (int off = 32; off > 0; off >>= 1) m = fmaxf(m, __shfl_xor(m, off));
    float e = expf(v - m);
    float s = e;
    for (int off = 32; off > 0; off >>= 1) s += __shfl_xor(s, off);
    wsh[t] = e / s;
  }
  xs[t] = x[(size_t)blk * 256 + t];
  __syncthreads();

  // nw: wave w handles n = w+4k, lane l holds float4 of cols 4l..4l+3
  const float4* nb4 = (const float4*)(nb + (size_t)b * 65536 + c * 256);
  float4 a4 = {0.f, 0.f, 0.f, 0.f};
  #pragma unroll
  for (int k = 0; k < 16; ++k) {
    int n = w + 4 * k;
    float4 v = nb4[(size_t)n * 256 + l];
    float wn = wsh[n];
    a4.x = fmaf(wn, v.x, a4.x);
    a4.y = fmaf(wn, v.y, a4.y);
    a4.z = fmaf(wn, v.z, a4.z);
    a4.w = fmaf(wn, v.w, a4.w);
  }
  *(float4*)&part[w][l * 4] = a4;
  __syncthreads();
  ns[t] = part[0][t] + part[1][t] + part[2][t] + part[3][t];
  __syncthreads();

  int j0 = l * 4;
  float4 xv = *(const float4*)&xs[j0];
  float4 nv = *(const float4*)&ns[j0];
  int i0 = w * 64;

  // pass 1: column sums of |g| (symmetric => equals row sums)
  float4 cs = {0.f, 0.f, 0.f, 0.f};
  #pragma unroll 4
  for (int ii = 0; ii < 64; ++ii) {
    int i = i0 + ii;
    float xi = xs[i], ni = ns[i];
    float v0 = fmaf(xi, nv.x, xv.x * ni);
    float v1 = fmaf(xi, nv.y, xv.y * ni);
    float v2 = fmaf(xi, nv.z, xv.z * ni);
    float v3 = fmaf(xi, nv.w, xv.w * ni);
    cs.x += (v0 != 0.f) ? __builtin_amdgcn_sqrtf(fmaxf(fabsf(v0), 1e-8f)) : 0.f;
    cs.y += (v1 != 0.f) ? __builtin_amdgcn_sqrtf(fmaxf(fabsf(v1), 1e-8f)) : 0.f;
    cs.z += (v2 != 0.f) ? __builtin_amdgcn_sqrtf(fmaxf(fabsf(v2), 1e-8f)) : 0.f;
    cs.w += (v3 != 0.f) ? __builtin_amdgcn_sqrtf(fmaxf(fabsf(v3), 1e-8f)) : 0.f;
  }
  *(float4*)&part[w][j0] = cs;
  __syncthreads();
  invs[t] = 1.f / (part[0][t] + part[1][t] + part[2][t] + part[3][t] + 1e-7f);
  nsArr[(size_t)blk * 256 + t] = ns[t];
  __syncthreads();
  invArr[(size_t)blk * 256 + t] = invs[t];

  // pass 2: h only (no adj stores)
  float4 ha = {0.f, 0.f, 0.f, 0.f};
  #pragma unroll 4
  for (int ii = 0; ii < 64; ++ii) {
    int i = i0 + ii;
    float xi = xs[i], ni = ns[i];
    float pix = invs[i] * xi;
    float v0 = fmaf(xi, nv.x, xv.x * ni);
    float v1 = fmaf(xi, nv.y, xv.y * ni);
    float v2 = fmaf(xi, nv.z, xv.z * ni);
    float v3 = fmaf(xi, nv.w, xv.w * ni);
    float g0 = (v0 != 0.f) ? copysignf(__builtin_amdgcn_sqrtf(fmaxf(fabsf(v0), 1e-8f)), v0) : 0.f;
    float g1 = (v1 != 0.f) ? copysignf(__builtin_amdgcn_sqrtf(fmaxf(fabsf(v1), 1e-8f)), v1) : 0.f;
    float g2 = (v2 != 0.f) ? copysignf(__builtin_amdgcn_sqrtf(fmaxf(fabsf(v2), 1e-8f)), v2) : 0.f;
    float g3 = (v3 != 0.f) ? copysignf(__builtin_amdgcn_sqrtf(fmaxf(fabsf(v3), 1e-8f)), v3) : 0.f;
    ha.x = fmaf(g0, pix, ha.x);
    ha.y = fmaf(g1, pix, ha.y);
    ha.z = fmaf(g2, pix, ha.z);
    ha.w = fmaf(g3, pix, ha.w);
  }
  __syncthreads();
  *(float4*)&part[w][j0] = ha;
  __syncthreads();
  float hsum = part[0][t] + part[1][t] + part[2][t] + part[3][t];
  zbf[(size_t)b * 2048 + c * 256 + t] = __float2bfloat16(hsum);
}

// ============ Kernel 3: adj store (barrier-light, pure write stream) ======
// 4096 blocks: bc = blk>>2 selects (b,c); q = blk&3 selects 64-row slab.
__global__ __launch_bounds__(256) void k_adj_store(
    const float* __restrict__ x, const float* __restrict__ nsArr,
    const float* __restrict__ invArr, float* __restrict__ adj)
{
  __shared__ float xs[256], ns[256], invs[256];
  int t = threadIdx.x;
  int w = t >> 6, l = t & 63;
  int blk = blockIdx.x;
  int bc = blk >> 2, q = blk & 3;

  xs[t]   = x[(size_t)bc * 256 + t];
  ns[t]   = nsArr[(size_t)bc * 256 + t];
  invs[t] = invArr[(size_t)bc * 256 + t];
  __syncthreads();

  int j0 = l * 4;
  float4 xv = *(const float4*)&xs[j0];
  float4 nv = *(const float4*)&ns[j0];
  float4 iv = *(const float4*)&invs[j0];
  float* ab = adj + (size_t)bc * 65536;
  int i0 = q * 64 + w * 16;

  #pragma unroll 4
  for (int ii = 0; ii < 16; ++ii) {
    int i = i0 + ii;
    float xi = xs[i], ni = ns[i];
    float v0 = fmaf(xi, nv.x, xv.x * ni);
    float v1 = fmaf(xi, nv.y, xv.y * ni);
    float v2 = fmaf(xi, nv.z, xv.z * ni);
    float v3 = fmaf(xi, nv.w, xv.w * ni);
    float g0 = (v0 != 0.f) ? copysignf(__builtin_amdgcn_sqrtf(fmaxf(fabsf(v0), 1e-8f)), v0) : 0.f;
    float g1 = (v1 != 0.f) ? copysignf(__builtin_amdgcn_sqrtf(fmaxf(fabsf(v1), 1e-8f)), v1) : 0.f;
    float g2 = (v2 != 0.f) ? copysignf(__builtin_amdgcn_sqrtf(fmaxf(fabsf(v2), 1e-8f)), v2) : 0.f;
    float g3 = (v3 != 0.f) ? copysignf(__builtin_amdgcn_sqrtf(fmaxf(fabsf(v3), 1e-8f)), v3) : 0.f;
    f32x4 o = { g0 * iv.x, g1 * iv.y, g2 * iv.z, g3 * iv.w };
    __builtin_nontemporal_store(o, (f32x4*)&ab[(size_t)i * 256 + j0]);
  }
}

// ============ Kernel 4: out = Z @ Wc^T (bf16 MFMA) ============
__global__ __launch_bounds__(256) void k_gemm(
    const __hip_bfloat16* __restrict__ zb, const __hip_bfloat16* __restrict__ Wcb,
    float* __restrict__ out)
{
  int tid = threadIdx.x;
  int wave = tid >> 6, lane = tid & 63;
  int g = lane >> 4, r = lane & 15;
  int bm = blockIdx.x & 7, bn = blockIdx.x >> 3;
  int m0 = bm * 32 + (wave & 1) * 16;
  int n0 = bn * 32 + (wave >> 1) * 16;

  const bf16x8* pa = (const bf16x8*)(zb  + (size_t)(m0 + r) * 2048 + g * 8);
  const bf16x8* pw = (const bf16x8*)(Wcb + (size_t)(n0 + r) * 2048 + g * 8);

  f32x4 acc0 = {0.f, 0.f, 0.f, 0.f}, acc1 = {0.f, 0.f, 0.f, 0.f};
  #pragma unroll 4
  for (int ks = 0; ks < 64; ks += 2) {
    bf16x8 a0 = pa[ks * 4];
    bf16x8 b0 = pw[ks * 4];
    bf16x8 a1 = pa[ks * 4 + 4];
    bf16x8 b1 = pw[ks * 4 + 4];
    acc0 = __builtin_amdgcn_mfma_f32_16x16x32_bf16(a0, b0, acc0, 0, 0, 0);
    acc1 = __builtin_amdgcn_mfma_f32_16x16x32_bf16(a1, b1, acc1, 0, 0, 0);
  }
  acc0 += acc1;
  #pragma unroll
  for (int q = 0; q < 4; ++q) {
    int row = m0 + g * 4 + q;
    __builtin_nontemporal_store(acc0[q], &out[(size_t)row * 2048 + n0 + r]);
  }
}

// ================= Fallback path (small ws) =================
__global__ __launch_bounds__(256) void k_scores_fb(
    const float* __restrict__ x, const float* __restrict__ nb,
    const float* __restrict__ W1, const float* __restrict__ W2,
    float* __restrict__ s1, float* __restrict__ s2)
{
  __shared__ float red[4];
  int t = threadIdx.x;
  int gid = blockIdx.x;
  float val;
  if (gid < NB * NN) {
    float w = W2[t] + W2[256 + t] + W2[512 + t] + W2[768 + t];
    const float* p = nb + (size_t)gid * 1024;
    val = w * (p[t] + p[256 + t] + p[512 + t] + p[768 + t]);
  } else {
    int b = gid - NB * NN;
    float w = W1[t] + W1[256 + t] + W1[512 + t] + W1[768 + t];
    const float* p = x + (size_t)b * 1024;
    val = w * (p[t] + p[256 + t] + p[512 + t] + p[768 + t]);
  }
  for (int off = 32; off > 0; off >>= 1) val += __shfl_down(val, off);
  if ((t & 63) == 0) red[t >> 6] = val;
  __syncthreads();
  if (t == 0) {
    float s = red[0] + red[1] + red[2] + red[3];
    if (gid < NB * NN) s2[gid] = s;
    else s1[gid - NB * NN] = s;
  }
}

__global__ __launch_bounds__(256) void k_adj_fb(
    const float* __restrict__ x, const float* __restrict__ nb,
    const float* __restrict__ s1, const float* __restrict__ s2,
    float* __restrict__ adj, float* __restrict__ hf)
{
  __shared__ float xs[256], ns[256], invs[256], wsh[64];
  __shared__ float part[4][256];
  int t = threadIdx.x;
  int w = t >> 6, l = t & 63;
  int blk = blockIdx.x;
  int b = blk >> 2, c = blk & 3;

  if (t < 64) {
    float v = s1[b] * s2[b * 64 + t];
    float m = v;
    for (int off = 32; off > 0; off >>= 1) m = fmaxf(m, __shfl_xor(m, off));
    float e = expf(v - m);
    float s = e;
    for (int off = 32; off > 0; off >>= 1) s += __shfl_xor(s, off);
    wsh[t] = e / s;
  }
  __syncthreads();
  float acc = 0.f;
  const float* pb = nb + (size_t)b * 65536 + c * 256 + t;
  #pragma unroll 8
  for (int n = 0; n < 64; ++n) acc = fmaf(wsh[n], pb[(size_t)n * 1024], acc);
  ns[t] = acc;
  xs[t] = x[(size_t)blk * 256 + t];
  __syncthreads();

  int j0 = l * 4;
  float4 xv = *(const float4*)&xs[j0];
  float4 nv = *(const float4*)&ns[j0];
  int i0 = w * 64;
  float4 cs = {0.f, 0.f, 0.f, 0.f};
  for (int ii = 0; ii < 64; ++ii) {
    int i = i0 + ii;
    float xi = xs[i], ni = ns[i];
    float v0 = fmaf(xi, nv.x, xv.x * ni);
    float v1 = fmaf(xi, nv.y, xv.y * ni);
    float v2 = fmaf(xi, nv.z, xv.z * ni);
    float v3 = fmaf(xi, nv.w, xv.w * ni);
    cs.x += (v0 != 0.f) ? __builtin_amdgcn_sqrtf(fmaxf(fabsf(v0), 1e-8f)) : 0.f;
    cs.y += (v1 != 0.f) ? __builtin_amdgcn_sqrtf(fmaxf(fabsf(v1), 1e-8f)) : 0.f;
    cs.z += (v2 != 0.f) ? __builtin_amdgcn_sqrtf(fmaxf(fabsf(v2), 1e-8f)) : 0.f;
    cs.w += (v3 != 0.f) ? __builtin_amdgcn_sqrtf(fmaxf(fabsf(v3), 1e-8f)) : 0.f;
  }
  *(float4*)&part[w][j0] = cs;
  __syncthreads();
  invs[t] = 1.f / (part[0][t] + part[1][t] + part[2][t] + part[3][t] + 1e-7f);
  __syncthreads();

  float4 iv = *(const float4*)&invs[j0];
  float4 ha = {0.f, 0.f, 0.f, 0.f};
  float* ab = adj + (size_t)blk * 65536;
  for (int ii = 0; ii < 64; ++ii) {
    int i = i0 + ii;
    float xi = xs[i], ni = ns[i];
    float pix = invs[i] * xi;
    float v0 = fmaf(xi, nv.x, xv.x * ni);
    float v1 = fmaf(xi, nv.y, xv.y * ni);
    float v2 = fmaf(xi, nv.z, xv.z * ni);
    float v3 = fmaf(xi, nv.w, xv.w * ni);
    float g0 = (v0 != 0.f) ? copysignf(__builtin_amdgcn_sqrtf(fmaxf(fabsf(v0), 1e-8f)), v0) : 0.f;
    float g1 = (v1 != 0.f) ? copysignf(__builtin_amdgcn_sqrtf(fmaxf(fabsf(v1), 1e-8f)), v1) : 0.f;
    float g2 = (v2 != 0.f) ? copysignf(__builtin_amdgcn_sqrtf(fmaxf(fabsf(v2), 1e-8f)), v2) : 0.f;
    float g3 = (v3 != 0.f) ? copysignf(__builtin_amdgcn_sqrtf(fmaxf(fabsf(v3), 1e-8f)), v3) : 0.f;
    f32x4 o = { g0 * iv.x, g1 * iv.y, g2 * iv.z, g3 * iv.w };
    __builtin_nontemporal_store(o, (f32x4*)&ab[(size_t)i * 256 + j0]);
    ha.x = fmaf(g0, pix, ha.x);
    ha.y = fmaf(g1, pix, ha.y);
    ha.z = fmaf(g2, pix, ha.z);
    ha.w = fmaf(g3, pix, ha.w);
  }
  __syncthreads();
  *(float4*)&part[w][j0] = ha;
  __syncthreads();
  hf[(size_t)blk * 256 + t] = part[0][t] + part[1][t] + part[2][t] + part[3][t];
}

__device__ inline bf16x8 cvt8_p(const float* p) {
  const float4* q = reinterpret_cast<const float4*>(p);
  float4 a = q[0], bq = q[1];
  bf16x8 r;
  r[0] = (__bf16)a.x;  r[1] = (__bf16)a.y;  r[2] = (__bf16)a.z;  r[3] = (__bf16)a.w;
  r[4] = (__bf16)bq.x; r[5] = (__bf16)bq.y; r[6] = (__bf16)bq.z; r[7] = (__bf16)bq.w;
  return r;
}

__global__ __launch_bounds__(256) void k_gemm_f32(
    const float* __restrict__ h, const float* __restrict__ x,
    const float* __restrict__ Wc, float* __restrict__ out)
{
  int tid = threadIdx.x;
  int wave = tid >> 6, lane = tid & 63;
  int g = lane >> 4, r = lane & 15;
  int bm = blockIdx.x & 3, bn = blockIdx.x >> 2;
  int m0 = bm * 64 + wave * 16;
  int n0 = bn * 32;
  int arow = m0 + r;
  int koff = g * 8;

  const float* za = h + (size_t)arow * 1024 + koff;
  const float* zb = x + (size_t)arow * 1024 + koff;
  const float* w0 = Wc + (size_t)(n0 + r) * 2048 + koff;
  const float* w1 = Wc + (size_t)(n0 + 16 + r) * 2048 + koff;

  f32x4 acc0 = {0.f, 0.f, 0.f, 0.f}, acc1 = {0.f, 0.f, 0.f, 0.f};
  #pragma unroll 4
  for (int ks = 0; ks < 32; ++ks) {
    acc0 = __builtin_amdgcn_mfma_f32_16x16x32_bf16(cvt8_p(za + ks * 32), cvt8_p(w0 + ks * 32), acc0, 0, 0, 0);
    acc1 = __builtin_amdgcn_mfma_f32_16x16x32_bf16(cvt8_p(za + ks * 32), cvt8_p(w1 + ks * 32), acc1, 0, 0, 0);
  }
  #pragma unroll 4
  for (int ks = 0; ks < 32; ++ks) {
    acc0 = __builtin_amdgcn_mfma_f32_16x16x32_bf16(cvt8_p(zb + ks * 32), cvt8_p(w0 + 1024 + ks * 32), acc0, 0, 0, 0);
    acc1 = __builtin_amdgcn_mfma_f32_16x16x32_bf16(cvt8_p(zb + ks * 32), cvt8_p(w1 + 1024 + ks * 32), acc1, 0, 0, 0);
  }
  #pragma unroll
  for (int q = 0; q < 4; ++q) {
    int row = m0 + g * 4 + q;
    out[(size_t)row * 2048 + n0 + r]      = acc0[q];
    out[(size_t)row * 2048 + n0 + 16 + r] = acc1[q];
  }
}

extern "C" void kernel_launch(void* const* d_in, const int* in_sizes, int n_in,
                              void* d_out, int out_size, void* d_ws, size_t ws_size,
                              hipStream_t stream) {
  const float* x  = (const float*)d_in[0];
  const float* nb = (const float*)d_in[1];
  const float* W1 = (const float*)d_in[2];
  const float* W2 = (const float*)d_in[3];
  const float* Wc = (const float*)d_in[4];
  float* out = (float*)d_out;
  float* adj = out + (size_t)NB * NO;

  char* ws = (char*)d_ws;
  const size_t ZBF_B = 1048576;        // 256*2048 bf16
  const size_t WCB_B = 8388608;        // 2048*2048 bf16
  // float region after bf16 buffers: s1(256) s2(16384) nsArr(262144) invArr(262144)
  const size_t FREG = (256 + 16384 + 262144 + 262144) * 4;
  bool fast = ws_size >= ZBF_B + WCB_B + FREG;

  if (fast) {
    __hip_bfloat16* zbf = (__hip_bfloat16*)ws;
    __hip_bfloat16* Wcb = (__hip_bfloat16*)(ws + ZBF_B);
    float* s1  = (float*)(ws + ZBF_B + WCB_B);
    float* s2  = s1 + 256;
    float* nsA = s2 + 16384;
    float* ivA = nsA + 262144;
    k_pre<<<20992, 256, 0, stream>>>(x, nb, W1, W2, Wc, Wcb, zbf, s1, s2);
    k_nw<<<NB * NC, 256, 0, stream>>>(x, nb, s1, s2, nsA, ivA, zbf);
    k_adj_store<<<4096, 256, 0, stream>>>(x, nsA, ivA, adj);
    k_gemm<<<512, 256, 0, stream>>>(zbf, Wcb, out);
  } else {
    float* hws = (float*)d_ws;
    float* s1  = hws + 262144;
    float* s2  = s1 + 256;
    k_scores_fb<<<NB * NN + NB, 256, 0, stream>>>(x, nb, W1, W2, s1, s2);
    k_adj_fb<<<NB * NC, 256, 0, stream>>>(x, nb, s1, s2, adj, hws);
    k_gemm_f32<<<256, 256, 0, stream>>>(hws, x, Wc, out);
  }
}

// Round 5
// 108.485 us; speedup vs baseline: 1.2649x; 1.2649x over previous
//
#include <hip/hip_runtime.h>
#include <hip/hip_bf16.h>
#include <math.h>

// B=256, C=4, N=64, F=256, OC=8, OF=256
// d_out = out (256*2048 f32) then adj (256*4*256*256 f32).

typedef __bf16 bf16x8 __attribute__((ext_vector_type(8)));
typedef __bf16 bf16x4 __attribute__((ext_vector_type(4)));
typedef float f32x4 __attribute__((ext_vector_type(4)));

#define NB 256
#define NC 4
#define NN 64
#define NF 256
#define NO 2048

// ============ Kernel 1 (fused): s1, s2, Wc->bf16, x->zbf ============
// blocks [0,16384): s2[b,n]   [16384,16640): s1[b]
// blocks [16640,20736): cvt Wc   [20736,20992): cvt x into zbf[:,1024:]
__global__ __launch_bounds__(256) void k_pre(
    const float* __restrict__ x, const float* __restrict__ nb,
    const float* __restrict__ W1, const float* __restrict__ W2,
    const float* __restrict__ Wc,
    __hip_bfloat16* __restrict__ Wcb, __hip_bfloat16* __restrict__ zbf,
    float* __restrict__ s1, float* __restrict__ s2)
{
  __shared__ float red[4];
  int t = threadIdx.x;
  int gid = blockIdx.x;

  if (gid < 16640) {
    int fi = t & 63;
    const float4* Wf4 = (const float4*)((gid < 16384) ? W2 : W1);
    float4 w0 = Wf4[fi], w1 = Wf4[64 + fi], w2 = Wf4[128 + fi], w3 = Wf4[192 + fi];
    float4 wv = { w0.x + w1.x + w2.x + w3.x,
                  w0.y + w1.y + w2.y + w3.y,
                  w0.z + w1.z + w2.z + w3.z,
                  w0.w + w1.w + w2.w + w3.w };
    const float4* src = (gid < 16384) ? ((const float4*)nb + (size_t)gid * 256)
                                      : ((const float4*)x + (size_t)(gid - 16384) * 256);
    float4 nv = src[t];
    float val = fmaf(nv.x, wv.x, fmaf(nv.y, wv.y, fmaf(nv.z, wv.z, nv.w * wv.w)));
    for (int off = 32; off > 0; off >>= 1) val += __shfl_down(val, off);
    if ((t & 63) == 0) red[t >> 6] = val;
    __syncthreads();
    if (t == 0) {
      float s = red[0] + red[1] + red[2] + red[3];
      if (gid < 16384) s2[gid] = s;
      else s1[gid - 16384] = s;
    }
  } else if (gid < 20736) {
    int idx = (gid - 16640) * 256 + t;
    float4 v = ((const float4*)Wc)[idx];
    bf16x4 o = { (__bf16)v.x, (__bf16)v.y, (__bf16)v.z, (__bf16)v.w };
    ((bf16x4*)Wcb)[idx] = o;
  } else {
    int i = (gid - 20736) * 256 + t;
    int e = i * 4;
    int b = e >> 10, r = e & 1023;
    float4 v = ((const float4*)x)[i];
    bf16x4 o = { (__bf16)v.x, (__bf16)v.y, (__bf16)v.z, (__bf16)v.w };
    *(bf16x4*)(zbf + (size_t)b * 2048 + 1024 + r) = o;
  }
}

// ============ Kernel 2: adj + h (monolithic — compute overlaps stores) ====
// One block per (b,c). fadj_sym symmetric -> column normalizer == row sum.
// Wave w owns rows w*64..w*64+63; lane l owns cols 4l..4l+3.
__global__ __launch_bounds__(256) void k_adj(
    const float* __restrict__ x, const float* __restrict__ nb,
    const float* __restrict__ s1, const float* __restrict__ s2,
    float* __restrict__ adj, __hip_bfloat16* __restrict__ zbf)
{
  __shared__ float xs[256], ns[256], invs[256], wsh[64];
  __shared__ float part[4][256];
  int t = threadIdx.x;
  int w = t >> 6, l = t & 63;
  int blk = blockIdx.x;
  int b = blk >> 2, c = blk & 3;

  if (t < 64) {
    float v = s1[b] * s2[b * 64 + t];
    float m = v;
    for (int off = 32; off > 0; off >>= 1) m = fmaxf(m, __shfl_xor(m, off));
    float e = expf(v - m);
    float s = e;
    for (int off = 32; off > 0; off >>= 1) s += __shfl_xor(s, off);
    wsh[t] = e / s;
  }
  xs[t] = x[(size_t)blk * 256 + t];
  __syncthreads();

  // nw gather: wave w handles n = w+4k, lane l holds float4 of cols 4l..4l+3
  const float4* nb4 = (const float4*)(nb + (size_t)b * 65536 + c * 256);
  float4 a4 = {0.f, 0.f, 0.f, 0.f};
  #pragma unroll
  for (int k = 0; k < 16; ++k) {
    int n = w + 4 * k;
    float4 v = nb4[(size_t)n * 256 + l];
    float wn = wsh[n];
    a4.x = fmaf(wn, v.x, a4.x);
    a4.y = fmaf(wn, v.y, a4.y);
    a4.z = fmaf(wn, v.z, a4.z);
    a4.w = fmaf(wn, v.w, a4.w);
  }
  *(float4*)&part[w][l * 4] = a4;
  __syncthreads();
  ns[t] = part[0][t] + part[1][t] + part[2][t] + part[3][t];
  __syncthreads();

  int j0 = l * 4;
  float4 xv = *(const float4*)&xs[j0];
  float4 nv = *(const float4*)&ns[j0];
  int i0 = w * 64;

  // pass 1: column sums of |g| (symmetric => equals row sums)
  float4 cs = {0.f, 0.f, 0.f, 0.f};
  #pragma unroll 4
  for (int ii = 0; ii < 64; ++ii) {
    int i = i0 + ii;
    float xi = xs[i], ni = ns[i];
    float v0 = fmaf(xi, nv.x, xv.x * ni);
    float v1 = fmaf(xi, nv.y, xv.y * ni);
    float v2 = fmaf(xi, nv.z, xv.z * ni);
    float v3 = fmaf(xi, nv.w, xv.w * ni);
    cs.x += (v0 != 0.f) ? __builtin_amdgcn_sqrtf(fmaxf(fabsf(v0), 1e-8f)) : 0.f;
    cs.y += (v1 != 0.f) ? __builtin_amdgcn_sqrtf(fmaxf(fabsf(v1), 1e-8f)) : 0.f;
    cs.z += (v2 != 0.f) ? __builtin_amdgcn_sqrtf(fmaxf(fabsf(v2), 1e-8f)) : 0.f;
    cs.w += (v3 != 0.f) ? __builtin_amdgcn_sqrtf(fmaxf(fabsf(v3), 1e-8f)) : 0.f;
  }
  *(float4*)&part[w][j0] = cs;
  __syncthreads();
  invs[t] = 1.f / (part[0][t] + part[1][t] + part[2][t] + part[3][t] + 1e-7f);
  __syncthreads();

  // pass 2: store adj (nt) + accumulate h
  float4 iv = *(const float4*)&invs[j0];
  float4 ha = {0.f, 0.f, 0.f, 0.f};
  float* ab = adj + (size_t)blk * 65536;
  #pragma unroll 4
  for (int ii = 0; ii < 64; ++ii) {
    int i = i0 + ii;
    float xi = xs[i], ni = ns[i];
    float pix = invs[i] * xi;
    float v0 = fmaf(xi, nv.x, xv.x * ni);
    float v1 = fmaf(xi, nv.y, xv.y * ni);
    float v2 = fmaf(xi, nv.z, xv.z * ni);
    float v3 = fmaf(xi, nv.w, xv.w * ni);
    float g0 = (v0 != 0.f) ? copysignf(__builtin_amdgcn_sqrtf(fmaxf(fabsf(v0), 1e-8f)), v0) : 0.f;
    float g1 = (v1 != 0.f) ? copysignf(__builtin_amdgcn_sqrtf(fmaxf(fabsf(v1), 1e-8f)), v1) : 0.f;
    float g2 = (v2 != 0.f) ? copysignf(__builtin_amdgcn_sqrtf(fmaxf(fabsf(v2), 1e-8f)), v2) : 0.f;
    float g3 = (v3 != 0.f) ? copysignf(__builtin_amdgcn_sqrtf(fmaxf(fabsf(v3), 1e-8f)), v3) : 0.f;
    f32x4 o = { g0 * iv.x, g1 * iv.y, g2 * iv.z, g3 * iv.w };
    __builtin_nontemporal_store(o, (f32x4*)&ab[(size_t)i * 256 + j0]);
    ha.x = fmaf(g0, pix, ha.x);
    ha.y = fmaf(g1, pix, ha.y);
    ha.z = fmaf(g2, pix, ha.z);
    ha.w = fmaf(g3, pix, ha.w);
  }
  __syncthreads();
  *(float4*)&part[w][j0] = ha;
  __syncthreads();
  float hsum = part[0][t] + part[1][t] + part[2][t] + part[3][t];
  zbf[(size_t)b * 2048 + c * 256 + t] = __float2bfloat16(hsum);
}

// ============ Kernel 3: out = Z @ Wc^T (bf16 MFMA) ============
__global__ __launch_bounds__(256) void k_gemm(
    const __hip_bfloat16* __restrict__ zb, const __hip_bfloat16* __restrict__ Wcb,
    float* __restrict__ out)
{
  int tid = threadIdx.x;
  int wave = tid >> 6, lane = tid & 63;
  int g = lane >> 4, r = lane & 15;
  int bm = blockIdx.x & 7, bn = blockIdx.x >> 3;
  int m0 = bm * 32 + (wave & 1) * 16;
  int n0 = bn * 32 + (wave >> 1) * 16;

  const bf16x8* pa = (const bf16x8*)(zb  + (size_t)(m0 + r) * 2048 + g * 8);
  const bf16x8* pw = (const bf16x8*)(Wcb + (size_t)(n0 + r) * 2048 + g * 8);

  f32x4 acc0 = {0.f, 0.f, 0.f, 0.f}, acc1 = {0.f, 0.f, 0.f, 0.f};
  #pragma unroll 4
  for (int ks = 0; ks < 64; ks += 2) {
    bf16x8 a0 = pa[ks * 4];
    bf16x8 b0 = pw[ks * 4];
    bf16x8 a1 = pa[ks * 4 + 4];
    bf16x8 b1 = pw[ks * 4 + 4];
    acc0 = __builtin_amdgcn_mfma_f32_16x16x32_bf16(a0, b0, acc0, 0, 0, 0);
    acc1 = __builtin_amdgcn_mfma_f32_16x16x32_bf16(a1, b1, acc1, 0, 0, 0);
  }
  acc0 += acc1;
  #pragma unroll
  for (int q = 0; q < 4; ++q) {
    int row = m0 + g * 4 + q;
    __builtin_nontemporal_store(acc0[q], &out[(size_t)row * 2048 + n0 + r]);
  }
}

// ================= Fallback path (small ws) =================
__global__ __launch_bounds__(256) void k_scores_fb(
    const float* __restrict__ x, const float* __restrict__ nb,
    const float* __restrict__ W1, const float* __restrict__ W2,
    float* __restrict__ s1, float* __restrict__ s2)
{
  __shared__ float red[4];
  int t = threadIdx.x;
  int gid = blockIdx.x;
  float val;
  if (gid < NB * NN) {
    float w = W2[t] + W2[256 + t] + W2[512 + t] + W2[768 + t];
    const float* p = nb + (size_t)gid * 1024;
    val = w * (p[t] + p[256 + t] + p[512 + t] + p[768 + t]);
  } else {
    int b = gid - NB * NN;
    float w = W1[t] + W1[256 + t] + W1[512 + t] + W1[768 + t];
    const float* p = x + (size_t)b * 1024;
    val = w * (p[t] + p[256 + t] + p[512 + t] + p[768 + t]);
  }
  for (int off = 32; off > 0; off >>= 1) val += __shfl_down(val, off);
  if ((t & 63) == 0) red[t >> 6] = val;
  __syncthreads();
  if (t == 0) {
    float s = red[0] + red[1] + red[2] + red[3];
    if (gid < NB * NN) s2[gid] = s;
    else s1[gid - NB * NN] = s;
  }
}

__global__ __launch_bounds__(256) void k_adj_fb(
    const float* __restrict__ x, const float* __restrict__ nb,
    const float* __restrict__ s1, const float* __restrict__ s2,
    float* __restrict__ adj, float* __restrict__ hf)
{
  __shared__ float xs[256], ns[256], invs[256], wsh[64];
  __shared__ float part[4][256];
  int t = threadIdx.x;
  int w = t >> 6, l = t & 63;
  int blk = blockIdx.x;
  int b = blk >> 2, c = blk & 3;

  if (t < 64) {
    float v = s1[b] * s2[b * 64 + t];
    float m = v;
    for (int off = 32; off > 0; off >>= 1) m = fmaxf(m, __shfl_xor(m, off));
    float e = expf(v - m);
    float s = e;
    for (int off = 32; off > 0; off >>= 1) s += __shfl_xor(s, off);
    wsh[t] = e / s;
  }
  __syncthreads();
  float acc = 0.f;
  const float* pb = nb + (size_t)b * 65536 + c * 256 + t;
  #pragma unroll 8
  for (int n = 0; n < 64; ++n) acc = fmaf(wsh[n], pb[(size_t)n * 1024], acc);
  ns[t] = acc;
  xs[t] = x[(size_t)blk * 256 + t];
  __syncthreads();

  int j0 = l * 4;
  float4 xv = *(const float4*)&xs[j0];
  float4 nv = *(const float4*)&ns[j0];
  int i0 = w * 64;
  float4 cs = {0.f, 0.f, 0.f, 0.f};
  for (int ii = 0; ii < 64; ++ii) {
    int i = i0 + ii;
    float xi = xs[i], ni = ns[i];
    float v0 = fmaf(xi, nv.x, xv.x * ni);
    float v1 = fmaf(xi, nv.y, xv.y * ni);
    float v2 = fmaf(xi, nv.z, xv.z * ni);
    float v3 = fmaf(xi, nv.w, xv.w * ni);
    cs.x += (v0 != 0.f) ? __builtin_amdgcn_sqrtf(fmaxf(fabsf(v0), 1e-8f)) : 0.f;
    cs.y += (v1 != 0.f) ? __builtin_amdgcn_sqrtf(fmaxf(fabsf(v1), 1e-8f)) : 0.f;
    cs.z += (v2 != 0.f) ? __builtin_amdgcn_sqrtf(fmaxf(fabsf(v2), 1e-8f)) : 0.f;
    cs.w += (v3 != 0.f) ? __builtin_amdgcn_sqrtf(fmaxf(fabsf(v3), 1e-8f)) : 0.f;
  }
  *(float4*)&part[w][j0] = cs;
  __syncthreads();
  invs[t] = 1.f / (part[0][t] + part[1][t] + part[2][t] + part[3][t] + 1e-7f);
  __syncthreads();

  float4 iv = *(const float4*)&invs[j0];
  float4 ha = {0.f, 0.f, 0.f, 0.f};
  float* ab = adj + (size_t)blk * 65536;
  for (int ii = 0; ii < 64; ++ii) {
    int i = i0 + ii;
    float xi = xs[i], ni = ns[i];
    float pix = invs[i] * xi;
    float v0 = fmaf(xi, nv.x, xv.x * ni);
    float v1 = fmaf(xi, nv.y, xv.y * ni);
    float v2 = fmaf(xi, nv.z, xv.z * ni);
    float v3 = fmaf(xi, nv.w, xv.w * ni);
    float g0 = (v0 != 0.f) ? copysignf(__builtin_amdgcn_sqrtf(fmaxf(fabsf(v0), 1e-8f)), v0) : 0.f;
    float g1 = (v1 != 0.f) ? copysignf(__builtin_amdgcn_sqrtf(fmaxf(fabsf(v1), 1e-8f)), v1) : 0.f;
    float g2 = (v2 != 0.f) ? copysignf(__builtin_amdgcn_sqrtf(fmaxf(fabsf(v2), 1e-8f)), v2) : 0.f;
    float g3 = (v3 != 0.f) ? copysignf(__builtin_amdgcn_sqrtf(fmaxf(fabsf(v3), 1e-8f)), v3) : 0.f;
    f32x4 o = { g0 * iv.x, g1 * iv.y, g2 * iv.z, g3 * iv.w };
    __builtin_nontemporal_store(o, (f32x4*)&ab[(size_t)i * 256 + j0]);
    ha.x = fmaf(g0, pix, ha.x);
    ha.y = fmaf(g1, pix, ha.y);
    ha.z = fmaf(g2, pix, ha.z);
    ha.w = fmaf(g3, pix, ha.w);
  }
  __syncthreads();
  *(float4*)&part[w][j0] = ha;
  __syncthreads();
  hf[(size_t)blk * 256 + t] = part[0][t] + part[1][t] + part[2][t] + part[3][t];
}

__device__ inline bf16x8 cvt8_p(const float* p) {
  const float4* q = reinterpret_cast<const float4*>(p);
  float4 a = q[0], bq = q[1];
  bf16x8 r;
  r[0] = (__bf16)a.x;  r[1] = (__bf16)a.y;  r[2] = (__bf16)a.z;  r[3] = (__bf16)a.w;
  r[4] = (__bf16)bq.x; r[5] = (__bf16)bq.y; r[6] = (__bf16)bq.z; r[7] = (__bf16)bq.w;
  return r;
}

__global__ __launch_bounds__(256) void k_gemm_f32(
    const float* __restrict__ h, const float* __restrict__ x,
    const float* __restrict__ Wc, float* __restrict__ out)
{
  int tid = threadIdx.x;
  int wave = tid >> 6, lane = tid & 63;
  int g = lane >> 4, r = lane & 15;
  int bm = blockIdx.x & 3, bn = blockIdx.x >> 2;
  int m0 = bm * 64 + wave * 16;
  int n0 = bn * 32;
  int arow = m0 + r;
  int koff = g * 8;

  const float* za = h + (size_t)arow * 1024 + koff;
  const float* zb = x + (size_t)arow * 1024 + koff;
  const float* w0 = Wc + (size_t)(n0 + r) * 2048 + koff;
  const float* w1 = Wc + (size_t)(n0 + 16 + r) * 2048 + koff;

  f32x4 acc0 = {0.f, 0.f, 0.f, 0.f}, acc1 = {0.f, 0.f, 0.f, 0.f};
  #pragma unroll 4
  for (int ks = 0; ks < 32; ++ks) {
    acc0 = __builtin_amdgcn_mfma_f32_16x16x32_bf16(cvt8_p(za + ks * 32), cvt8_p(w0 + ks * 32), acc0, 0, 0, 0);
    acc1 = __builtin_amdgcn_mfma_f32_16x16x32_bf16(cvt8_p(za + ks * 32), cvt8_p(w1 + ks * 32), acc1, 0, 0, 0);
  }
  #pragma unroll 4
  for (int ks = 0; ks < 32; ++ks) {
    acc0 = __builtin_amdgcn_mfma_f32_16x16x32_bf16(cvt8_p(zb + ks * 32), cvt8_p(w0 + 1024 + ks * 32), acc0, 0, 0, 0);
    acc1 = __builtin_amdgcn_mfma_f32_16x16x32_bf16(cvt8_p(zb + ks * 32), cvt8_p(w1 + 1024 + ks * 32), acc1, 0, 0, 0);
  }
  #pragma unroll
  for (int q = 0; q < 4; ++q) {
    int row = m0 + g * 4 + q;
    out[(size_t)row * 2048 + n0 + r]      = acc0[q];
    out[(size_t)row * 2048 + n0 + 16 + r] = acc1[q];
  }
}

extern "C" void kernel_launch(void* const* d_in, const int* in_sizes, int n_in,
                              void* d_out, int out_size, void* d_ws, size_t ws_size,
                              hipStream_t stream) {
  const float* x  = (const float*)d_in[0];
  const float* nb = (const float*)d_in[1];
  const float* W1 = (const float*)d_in[2];
  const float* W2 = (const float*)d_in[3];
  const float* Wc = (const float*)d_in[4];
  float* out = (float*)d_out;
  float* adj = out + (size_t)NB * NO;

  char* ws = (char*)d_ws;
  const size_t ZBF_B = 1048576;        // 256*2048 bf16
  const size_t WCB_B = 8388608;        // 2048*2048 bf16
  const size_t FREG = (256 + 16384) * 4;
  bool fast = ws_size >= ZBF_B + WCB_B + FREG;

  if (fast) {
    __hip_bfloat16* zbf = (__hip_bfloat16*)ws;
    __hip_bfloat16* Wcb = (__hip_bfloat16*)(ws + ZBF_B);
    float* s1  = (float*)(ws + ZBF_B + WCB_B);
    float* s2  = s1 + 256;
    k_pre<<<20992, 256, 0, stream>>>(x, nb, W1, W2, Wc, Wcb, zbf, s1, s2);
    k_adj<<<NB * NC, 256, 0, stream>>>(x, nb, s1, s2, adj, zbf);
    k_gemm<<<512, 256, 0, stream>>>(zbf, Wcb, out);
  } else {
    float* hws = (float*)d_ws;
    float* s1  = hws + 262144;
    float* s2  = s1 + 256;
    k_scores_fb<<<NB * NN + NB, 256, 0, stream>>>(x, nb, W1, W2, s1, s2);
    k_adj_fb<<<NB * NC, 256, 0, stream>>>(x, nb, s1, s2, adj, hws);
    k_gemm_f32<<<256, 256, 0, stream>>>(hws, x, Wc, out);
  }
}